// Round 1
// baseline (88.468 us; speedup 1.0000x reference)
//
#include <hip/hip_runtime.h>
#include <math.h>

// DiffRenderer: BS=4, IMG=64, D_STEPS=64, D_SH=61, H1=128
// Inputs: z_shape(4,61), z_extr(4,5), W1(64,128), b1(128), W2(128,1), b2(1)
// Output: depth_pred (4*64*64) ++ occ (4*64*64), fp32
//
// Round N+1 changes vs the 87.4 µs kernel:
//  1. precompute_cvec FUSED into render kernel: each block recomputes its
//     batch's cvec[128] into LDS with the EXACT same serial fmaf chain
//     (b1[h] then f=0..60), so values are bit-identical. This removes the
//     single-block cold-HBM kernel + launch gap (~3 µs), and leaves d_ws
//     completely unused.
//  2. Early exit for waves with no zero-crossing: ballot on acc (sign(tanh(x))
//     == sign(x), tanh(0)=0), skip tanhf + the 24-swizzle butterfly reduction
//     when cross==0. Used values remain bit-identical.
//  All FP chains feeding outputs are instruction-identical to the passing
//  kernel (absmax 0.0): no reassociation anywhere.

#define N_RAYS (4 * 64 * 64)

typedef float v2f __attribute__((ext_vector_type(2)));
typedef float f4v __attribute__((ext_vector_type(4)));

static __device__ __forceinline__ v2f mk2(float a, float b) {
    v2f r; r.x = a; r.y = b; return r;
}

// scalar load of 4 dwords into SGPRs; ptr must be wave-uniform, 16B-aligned
#define SLOAD4(dst, ptr) \
    asm volatile("s_load_dwordx4 %0, %1, 0x0" : "=s"(dst) : "s"(ptr))

__global__ __launch_bounds__(256, 8) void render_fused(
    const float* __restrict__ z_shape,   // (4,61)
    const float* __restrict__ z_extr,    // (4,5): scale, tx, ty, tz, alpha
    const float* __restrict__ W1,        // (64,128) row-major
    const float* __restrict__ b1,        // (128)
    const float* __restrict__ W2,        // (128,1)
    const float* __restrict__ b2,        // (1)
    float* __restrict__ out)             // depth[16384] then occ[16384]
{
    __shared__ __align__(16) float cvec_lds[128];

    const int tid  = threadIdx.x;
    const int lane = tid & 63;
    const int wave = __builtin_amdgcn_readfirstlane(tid >> 6);
    const int ray  = blockIdx.x * 4 + wave;       // 0..16383
    const int b    = ray >> 12;                   // batch
    const int rem  = ray & 4095;
    const int yi   = rem >> 6;                    // pixel row (y)
    const int xj   = rem & 63;                    // pixel col (x)

    // ---- fused cvec: threads 0..127 compute cvec[h] = b1[h] + sum_f
    //      z_shape[bb,f] * W1[3+f,h], SAME serial chain as the old kernel 1.
    //      4096 blocks / batch-of-1024 => whole block shares one batch.
    if (tid < 128) {
        const int h  = tid;
        const int bb = blockIdx.x >> 10;          // block-uniform batch
        const float* __restrict__ zs = z_shape + bb * 61;
        float a = b1[h];
        #pragma unroll 4
        for (int f = 0; f < 61; ++f)
            a = fmaf(zs[f], W1[(3 + f) * 128 + h], a);
        cvec_lds[h] = a;
    }

    // per-batch extrinsics (wave-uniform) — independent of the cvec compute,
    // scheduled before the barrier so latency overlaps.
    const float scale = z_extr[b * 5 + 0];
    const float tx    = z_extr[b * 5 + 1];
    const float ty    = z_extr[b * 5 + 2];
    const float tz    = z_extr[b * 5 + 3];
    const float alpha = z_extr[b * 5 + 4];

    const float a  = 3.14159274101257324f * alpha;   // fp32(pi) * alpha
    const float ca = cosf(a);
    const float sa = sinf(a);
    const float s_obj = 1.0f / scale;                // reference: 1/z_extr[:,0]
    const float s_inv = 1.0f / s_obj;                // reference: 1/s_obj
    const float T = tz + 2.5f;                       // bb_depth

    // depth sample for this lane
    const float step = 2.0f / 63.0f;
    const float zk  = -1.0f + (float)lane * step;
    const float Z   = zk * s_inv + T;                // camera-space depth
    const float zk1 = -1.0f + (float)(lane + 1) * step;
    const float Z1  = zk1 * s_inv + T;

    // pixel -> camera ray direction via K_inv: [(x-c)/f, (y-c)/f, 1]
    const float kf  = 1.0f / 70.0f;
    const float kc  = -(31.5f / 70.0f);
    const float u = fmaf((float)xj, kf, kc);
    const float v = fmaf((float)yi, kf, kc);

    // world point = depth * K_inv*p - t  (R_t = I, t = [0,0,2.5])
    // object coords = s_obj * R_obj @ (world - t_obj)
    const float qx = Z * u - tx;
    const float qy = Z * v - ty;
    const float qz = (Z - 2.5f) - tz;
    const float X0 = s_obj * (ca * qx - sa * qy);
    const float X1 = s_obj * (sa * qx + ca * qy);
    const float X2 = s_obj * qz;

    const v2f X0v = mk2(X0, X0);
    const v2f X1v = mk2(X1, X1);
    const v2f X2v = mk2(X2, X2);
    const v2f zero2 = mk2(0.0f, 0.0f);

    __syncthreads();                                 // cvec_lds ready

    // MLP: acc = b2 + sum_j relu(fma(X0,w0j, fma(X1,w1j, fma(X2,w2j, c_j)))) * w2j
    // 16 chunks of 8 neurons; W1/W2 land in SGPRs (scalar pipe), cvec from LDS
    // (wave-uniform address -> broadcast, no bank conflict).
    float acc = b2[0];
    #pragma unroll 4
    for (int q = 0; q < 16; ++q) {
        const int o = q * 8;
        f4v a0l, a0h, a1l, a1h, a2l, a2h, wol, woh;
        SLOAD4(a0l, W1 + o);            SLOAD4(a0h, W1 + o + 4);
        SLOAD4(a1l, W1 + 128 + o);      SLOAD4(a1h, W1 + 128 + o + 4);
        SLOAD4(a2l, W1 + 256 + o);      SLOAD4(a2h, W1 + 256 + o + 4);
        SLOAD4(wol, W2 + o);            SLOAD4(woh, W2 + o + 4);
        const f4v ccl = *(const f4v*)(cvec_lds + o);
        const f4v cch = *(const f4v*)(cvec_lds + o + 4);
        // SMEM returns out of order -> full drain, tied to all loaded regs so
        // no use can be scheduled before the wait. (Also covers the ds_reads;
        // the compiler additionally inserts its own lgkmcnt for those.)
        asm volatile("s_waitcnt lgkmcnt(0)"
                     : "+s"(a0l), "+s"(a0h), "+s"(a1l), "+s"(a1h),
                       "+s"(a2l), "+s"(a2h), "+s"(wol), "+s"(woh));

        // neurons o+0..o+3
        {
            v2f lo = __builtin_elementwise_fma(X2v, mk2(a2l.x, a2l.y), mk2(ccl.x, ccl.y));
            lo = __builtin_elementwise_fma(X1v, mk2(a1l.x, a1l.y), lo);
            lo = __builtin_elementwise_fma(X0v, mk2(a0l.x, a0l.y), lo);
            lo = __builtin_elementwise_max(lo, zero2);
            v2f hi = __builtin_elementwise_fma(X2v, mk2(a2l.z, a2l.w), mk2(ccl.z, ccl.w));
            hi = __builtin_elementwise_fma(X1v, mk2(a1l.z, a1l.w), hi);
            hi = __builtin_elementwise_fma(X0v, mk2(a0l.z, a0l.w), hi);
            hi = __builtin_elementwise_max(hi, zero2);
            acc = fmaf(lo.x, wol.x, acc);
            acc = fmaf(lo.y, wol.y, acc);
            acc = fmaf(hi.x, wol.z, acc);
            acc = fmaf(hi.y, wol.w, acc);
        }
        // neurons o+4..o+7
        {
            v2f lo = __builtin_elementwise_fma(X2v, mk2(a2h.x, a2h.y), mk2(cch.x, cch.y));
            lo = __builtin_elementwise_fma(X1v, mk2(a1h.x, a1h.y), lo);
            lo = __builtin_elementwise_fma(X0v, mk2(a0h.x, a0h.y), lo);
            lo = __builtin_elementwise_max(lo, zero2);
            v2f hi = __builtin_elementwise_fma(X2v, mk2(a2h.z, a2h.w), mk2(cch.z, cch.w));
            hi = __builtin_elementwise_fma(X1v, mk2(a1h.z, a1h.w), hi);
            hi = __builtin_elementwise_fma(X0v, mk2(a0h.z, a0h.w), hi);
            hi = __builtin_elementwise_max(hi, zero2);
            acc = fmaf(lo.x, woh.x, acc);
            acc = fmaf(lo.y, woh.y, acc);
            acc = fmaf(hi.x, woh.z, acc);
            acc = fmaf(hi.y, woh.w, acc);
        }
    }

    // zero-crossing detection along depth (lane axis).
    // sign(tanh(x)) == sign(x) and tanh(0)=0, so ballot on acc directly —
    // lets crossing-free waves skip tanhf + the butterfly entirely.
    const unsigned long long mask  = __ballot(acc > 0.0f);
    const unsigned long long cross = mask & ~(mask >> 1) & 0x7fffffffffffffffULL;

    if (cross == 0ULL) {
        if (lane == 0) {
            out[ray]          = 0.0f;   // depth_pred
            out[N_RAYS + ray] = 0.0f;   // occ
        }
        return;
    }

    const float sdf = tanhf(acc);
    const bool isC = (cross >> lane) & 1ULL;
    const float sdf_next = __shfl_down(sdf, 1, 64);

    float d1 = isC ? Z        : 100.0f;
    float d2 = isC ? Z1       : 100.0f;
    float s1 = isC ? sdf      : 0.0f;
    float s2 = isC ? sdf_next : 0.0f;

    #pragma unroll
    for (int m = 1; m < 64; m <<= 1) {
        d1 = fminf(d1, __shfl_xor(d1, m, 64));
        d2 = fminf(d2, __shfl_xor(d2, m, 64));
        s1 += __shfl_xor(s1, m, 64);
        s2 += __shfl_xor(s2, m, 64);
    }

    if (lane == 0) {
        out[ray]          = d1 - s1 / (s2 - s1 - 1e-6f) * (d2 - d1);
        out[N_RAYS + ray] = 1.0f;
    }
}

extern "C" void kernel_launch(void* const* d_in, const int* in_sizes, int n_in,
                              void* d_out, int out_size, void* d_ws, size_t ws_size,
                              hipStream_t stream) {
    const float* z_shape = (const float*)d_in[0];   // (4,61)
    const float* z_extr  = (const float*)d_in[1];   // (4,5)
    const float* W1      = (const float*)d_in[2];   // (64,128)
    const float* b1      = (const float*)d_in[3];   // (128)
    const float* W2      = (const float*)d_in[4];   // (128,1)
    const float* b2      = (const float*)d_in[5];   // (1)
    float* out  = (float*)d_out;
    (void)d_ws; (void)ws_size;                      // workspace unused now

    render_fused<<<N_RAYS / 4, 256, 0, stream>>>(z_shape, z_extr, W1, b1, W2, b2, out);
}